// Round 8
// baseline (406.639 us; speedup 1.0000x reference)
//
#include <hip/hip_runtime.h>

#define BATCH 32
#define NRr 32
#define NFf 128
#define NHh 64
#define NFHh 64
#define TI 4

__device__ __forceinline__ float dot4(float4 a, float4 b) {
    return fmaf(a.x, b.x, fmaf(a.y, b.y, fmaf(a.z, b.z, a.w * b.w)));
}

// ---------------------------------------------------------------------------
// intra v14 (R6): CH=16, balanced XCD swizzle, merged pre_y tail on rh/fh
// blocks, G/H weight blocks at 576..607. Block 576 additionally zeroes the
// 32 per-batch flags used by the fused inter launch (same stream -> ordered).
// ---------------------------------------------------------------------------
__global__ __launch_bounds__(256, 4) void intra_kernel(
    const float* __restrict__ robot, const float* __restrict__ frontier,
    const float* __restrict__ rhist, const float* __restrict__ fhist,
    const float* __restrict__ Wq, const float* __restrict__ bq,
    const float* __restrict__ Wk, const float* __restrict__ bk,
    const float* __restrict__ Wv, const float* __restrict__ bv,
    const float* __restrict__ Wn1, const float* __restrict__ bn1,
    const float* __restrict__ Wn2, const float* __restrict__ bn2,
    const float* __restrict__ We1, const float* __restrict__ be1,
    float* __restrict__ o_robot, float* __restrict__ o_frontier,
    float* __restrict__ o_rh, float* __restrict__ o_fh,
    float* __restrict__ w5, float* __restrict__ yv5,
    float* __restrict__ w6, float* __restrict__ yv6,
    float* __restrict__ Gm, float* __restrict__ gvec,
    float* __restrict__ Hm, float* __restrict__ hbvec,
    unsigned* __restrict__ flags)
{
    __shared__ __align__(16) float sXc[512];    // chunk rows [16][32]
    __shared__ __align__(16) float sQ[512];     // q, then z, then out rows
    __shared__ __align__(16) float sQK[512];    // Wk^T q rows, then yk rows
    __shared__ __align__(16) float sAgg[512];   // agg rows
    __shared__ __align__(16) float sBig[6240];
    float* sS  = sBig;           // scores [16][P], P = N+4   (<=2112)
    float* sXT = sBig + 2112;    // x^T [32][P2], P2 = N+1    (<=4128)
    float* sT  = sBig;           // T [16][256] overlays after agg (4096)

    const int rawblk = blockIdx.x, tid = threadIdx.x;

    if (rawblk >= 576) {   // G/H fused-matrix blocks (weights only)
        if (rawblk == 576 && tid < 32) flags[tid] = 0u;   // reset flags
        const int hr = ((rawblk - 576) << 3) + (tid >> 5), e = tid & 31;
        const float* w1q = We1 + hr * 65;
        const float* w1k = w1q + 32;
        float aG = 0.f, aH = 0.f;
        #pragma unroll
        for (int d2 = 0; d2 < 32; ++d2) {
            aG = fmaf(w1q[d2], Wq[d2 * 32 + e], aG);
            aH = fmaf(w1k[d2], Wk[d2 * 32 + e], aH);
        }
        Gm[(hr << 5) + e] = aG;
        Hm[(hr << 5) + e] = aH;
        if (e == 0) {
            float ag = be1[hr], ahb = 0.f;
            #pragma unroll
            for (int d2 = 0; d2 < 32; ++d2) {
                ag  = fmaf(w1q[d2], bq[d2], ag);
                ahb = fmaf(w1k[d2], bk[d2], ahb);
            }
            gvec[hr] = ag;
            hbvec[hr] = ahb;
        }
        return;
    }

    // segment-balanced XCD swizzle: each XCD gets 8 robot / 32 frontier /
    // 16 rh / 16 fh slots, whole batches contiguous per XCD.
    const int xcd = rawblk & 7, slot = rawblk >> 3; // 0..71
    int blk;
    if (slot < 8)       blk = (xcd << 3) + slot;                // [0,64)
    else if (slot < 40) blk = 64  + (xcd << 5) + (slot - 8);    // [64,320)
    else if (slot < 56) blk = 320 + (xcd << 4) + (slot - 40);   // [320,448)
    else                blk = 448 + (xcd << 4) + (slot - 56);   // [448,576)

    const float* xin; float* xout; int N, lgN, b, chunk;
    float* wPre = nullptr; float* yvPre = nullptr;
    if (blk < 64)       { xin=robot;    xout=o_robot;    N=32;  lgN=5; b=blk>>1;       chunk=blk&1; }
    else if (blk < 320) { xin=frontier; xout=o_frontier; N=128; lgN=7; b=(blk-64)>>3;  chunk=(blk-64)&7; }
    else if (blk < 448) { xin=rhist;    xout=o_rh;       N=64;  lgN=6; b=(blk-320)>>2; chunk=(blk-320)&3; wPre=w5; yvPre=yv5; }
    else                { xin=fhist;    xout=o_fh;       N=64;  lgN=6; b=(blk-448)>>2; chunk=(blk-448)&3; wPre=w6; yvPre=yv6; }

    const int P = N + 4, P2 = N + 1;
    const float* xb = xin + (size_t)b * N * 32;
    const int r0 = chunk << 4;           // CH = 16
    const int d = tid & 31;
    const int rloc = tid >> 5;           // 0..7

    // stage chunk rows + full x^T
    sXc[tid] = xb[(r0 << 5) + tid];
    sXc[tid + 256] = xb[(r0 << 5) + tid + 256];
    for (int idx = tid; idx < (N << 5); idx += 256) {
        int j = idx >> 5, d2 = idx & 31;
        sXT[d2 * P2 + j] = xb[idx];
    }
    __syncthreads();

    // q[rr][d], rr in {rloc, rloc+8}
    {
        const float4* wq4 = (const float4*)(Wq + (d << 5));
        float4 wq[8];
        #pragma unroll
        for (int k = 0; k < 8; ++k) wq[k] = wq4[k];
        const float bqd = bq[d];
        #pragma unroll
        for (int p = 0; p < 2; ++p) {
            int rr = rloc + (p << 3);
            const float4* xr = (const float4*)(sXc + (rr << 5));
            float a = bqd;
            #pragma unroll
            for (int k = 0; k < 8; ++k) a += dot4(wq[k], xr[k]);
            sQ[(rr << 5) + d] = a;
        }
    }
    __syncthreads();

    // qk[rr][e] = sum_dd Wk[dd][e] * q[rr][dd]
    {
        #pragma unroll
        for (int p = 0; p < 2; ++p) {
            int rr = rloc + (p << 3);
            const float* qr = sQ + (rr << 5);
            float a = 0.f;
            #pragma unroll
            for (int dd2 = 0; dd2 < 32; ++dd2)
                a = fmaf(Wk[dd2 * 32 + d], qr[dd2], a);
            sQK[(rr << 5) + d] = a;
        }
    }
    __syncthreads();

    // scores [16][N]
    for (int idx = tid; idx < (16 << lgN); idx += 256) {
        int r = idx >> lgN, j = idx & (N - 1);
        const float* qr = sQK + (r << 5);
        float a = 0.f;
        #pragma unroll
        for (int e = 0; e < 32; ++e) a = fmaf(qr[e], sXT[e * P2 + j], a);
        sS[r * P + j] = a;
    }
    __syncthreads();

    // softmax: rows {rloc, rloc+8}, 32 lanes each
    {
        #pragma unroll
        for (int p = 0; p < 2; ++p) {
            int rr = rloc + (p << 3);
            float* row = sS + rr * P;
            float m = -1e30f;
            for (int j = d; j < N; j += 32) m = fmaxf(m, row[j]);
            #pragma unroll
            for (int msk = 16; msk; msk >>= 1) m = fmaxf(m, __shfl_xor(m, msk));
            float s = 0.f;
            for (int j = d; j < N; j += 32) { float ev = __expf(row[j] - m); row[j] = ev; s += ev; }
            #pragma unroll
            for (int msk = 16; msk; msk >>= 1) s += __shfl_xor(s, msk);
            float inv = 1.0f / s;
            for (int j = d; j < N; j += 32) row[j] *= inv;
        }
    }
    __syncthreads();

    // z[rr][d] = e_rr @ x[:, d]  (4 accumulators break the serial chain)
    {
        #pragma unroll
        for (int p = 0; p < 2; ++p) {
            int rr = rloc + (p << 3);
            const float* er = sS + rr * P;
            const float* xtr = sXT + d * P2;
            float a0 = 0.f, a1 = 0.f, a2 = 0.f, a3 = 0.f;
            for (int j = 0; j < N; j += 4) {
                a0 = fmaf(er[j],     xtr[j],     a0);
                a1 = fmaf(er[j + 1], xtr[j + 1], a1);
                a2 = fmaf(er[j + 2], xtr[j + 2], a2);
                a3 = fmaf(er[j + 3], xtr[j + 3], a3);
            }
            sQ[(rr << 5) + d] = (a0 + a1) + (a2 + a3);
        }
    }
    __syncthreads();

    // agg[rr][d] = Wv[d] . z[rr] + bv[d]
    {
        const float4* wv4 = (const float4*)(Wv + (d << 5));
        float4 wv[8];
        #pragma unroll
        for (int k = 0; k < 8; ++k) wv[k] = wv4[k];
        const float bvd = bv[d];
        #pragma unroll
        for (int p = 0; p < 2; ++p) {
            int rr = rloc + (p << 3);
            const float4* zr = (const float4*)(sQ + (rr << 5));
            float a = bvd;
            #pragma unroll
            for (int k = 0; k < 8; ++k) a += dot4(wv[k], zr[k]);
            sAgg[(rr << 5) + d] = a;
        }
    }
    __syncthreads();

    // node-MLP hidden: thread owns hid h=tid, loops 16 rows (w1r amortized)
    {
        const float4* w14 = (const float4*)(Wn1 + (tid << 6));
        float4 w1r[16];
        #pragma unroll
        for (int k = 0; k < 16; ++k) w1r[k] = w14[k];
        const float b1 = bn1[tid];
        #pragma unroll
        for (int r = 0; r < 16; ++r) {
            const float4* xr = (const float4*)(sXc + (r << 5));
            const float4* ar = (const float4*)(sAgg + (r << 5));
            float a = b1;
            #pragma unroll
            for (int k = 0; k < 8; ++k) a += dot4(w1r[k], xr[k]);
            #pragma unroll
            for (int k = 0; k < 8; ++k) a += dot4(w1r[8 + k], ar[k]);
            sT[(r << 8) + tid] = fmaxf(a, 0.f);
        }
    }
    __syncthreads();

    // out: thread (rg,d) does rows rg and rg+8 (w2r amortized over 2 rows)
    {
        const int rg = tid >> 5;
        float acc0 = 0.f, acc1 = 0.f;
        #pragma unroll
        for (int hc = 0; hc < 4; ++hc) {
            const float4* w24 = (const float4*)(Wn2 + (d << 8) + (hc << 6));
            float4 w2r[16];
            #pragma unroll
            for (int k = 0; k < 16; ++k) w2r[k] = w24[k];
            const float4* t0 = (const float4*)(sT + (rg << 8) + (hc << 6));
            const float4* t1 = (const float4*)(sT + ((rg + 8) << 8) + (hc << 6));
            #pragma unroll
            for (int k = 0; k < 16; ++k) {
                acc0 += dot4(w2r[k], t0[k]);
                acc1 += dot4(w2r[k], t1[k]);
            }
        }
        const float b2 = bn2[d];
        const size_t base = ((size_t)b * N) << 5;
        float o0 = sXc[(rg << 5) + d] + b2 + acc0;
        float o1 = sXc[((rg + 8) << 5) + d] + b2 + acc1;
        xout[base + ((r0 + rg) << 5) + d]     = o0;
        xout[base + ((r0 + rg + 8) << 5) + d] = o1;
        if (wPre) {                      // keep out rows for the pre tail
            sQ[(rg << 5) + d] = o0;
            sQ[((rg + 8) << 5) + d] = o1;
        }
    }

    // ---- merged pre_y tail (rh/fh blocks): w/yv for the inter launches ----
    if (wPre) {
        __syncthreads();
        // yk[rr] = Wk*out+bk -> sQK ; yv[rr] = Wv*out+bv -> global
        {
            const float4* wk4 = (const float4*)(Wk + (d << 5));
            const float4* wv4 = (const float4*)(Wv + (d << 5));
            const float bkd = bk[d], bvd = bv[d];
            #pragma unroll
            for (int p = 0; p < 2; ++p) {
                int rr = rloc + (p << 3);
                const float4* orow = (const float4*)(sQ + (rr << 5));
                float aK = bkd, aV = bvd;
                #pragma unroll
                for (int k = 0; k < 8; ++k) {
                    float4 o = orow[k];
                    aK += dot4(wk4[k], o);
                    aV += dot4(wv4[k], o);
                }
                sQK[(rr << 5) + d] = aK;
                yvPre[((size_t)(b * N + r0 + rr) << 5) + d] = aV;
            }
        }
        __syncthreads();
        // w[h][j] = We1[h,32:64] . yk[j]   (h = tid, j = r0..r0+15)
        {
            const float* w1 = We1 + tid * 65 + 32;
            float acc[16];
            #pragma unroll
            for (int jl = 0; jl < 16; ++jl) acc[jl] = 0.f;
            #pragma unroll
            for (int e = 0; e < 32; ++e) {
                float we = w1[e];
                #pragma unroll
                for (int jl = 0; jl < 16; ++jl)
                    acc[jl] = fmaf(we, sQK[(jl << 5) + e], acc[jl]);
            }
            float* wbase = wPre + (((size_t)b * 64 + (tid >> 2)) * N + r0) * 4 + (tid & 3);
            #pragma unroll
            for (int jl = 0; jl < 16; ++jl)
                wbase[jl << 2] = acc[jl];
        }
    }
}

// ---------------------------------------------------------------------------
// inter body (R6 inter v12, factored): one 4-row x-tile vs a y-side.
// wT layout: ((b*64+h/4)*Ny + j)*4 + h%4.
// ---------------------------------------------------------------------------
__device__ __forceinline__ void inter_body(
    const float* __restrict__ x, int Nx, const float* __restrict__ w,
    const float* __restrict__ yv, int Ny, const float* __restrict__ dis,
    float* __restrict__ outp, float* __restrict__ ep,
    float* __restrict__ wPre, float* __restrict__ yvPre, int idx,
    const float* __restrict__ Gm, const float* __restrict__ gvec,
    const float* __restrict__ Hm, const float* __restrict__ hbvec,
    const float* __restrict__ Wv, const float* __restrict__ bv,
    const float* __restrict__ We1, const float* __restrict__ We2,
    const float* __restrict__ Wn1, const float* __restrict__ bn1,
    const float* __restrict__ Wn2, const float* __restrict__ bn2,
    float* sX, float* sQ, float* sAgg, float* sDis, float* sC, float* sW2,
    float* sS, float* sUT, float* sPR)
{
    const int tid = threadIdx.x;
    const int lgNy = (Ny == 128) ? 7 : 6;
    const int tiles = Nx >> 2;
    const int b = idx / tiles, i0 = (idx - b * tiles) << 2;
    const float* xrow = x + ((size_t)(b * Nx + i0)) * 32;

    // phase 0: stage x, dis (yv stays in global/L2)
    if (tid < 128) sX[tid] = xrow[tid];
    if (tid < Ny) {
        int il = tid >> (lgNy - 2), jq = tid & ((Ny >> 2) - 1);
        ((float4*)sDis)[(il << 5) + jq] =
            ((const float4*)(dis + ((size_t)(b * Nx + i0 + il)) * Ny))[jq];
    }
    __syncthreads();

    // phase 2 (G-fused): u = G x + g ; c, w2
    {
        const float* grow = Gm + (tid << 5);
        const float g0 = gvec[tid];
        float acc[TI];
        #pragma unroll
        for (int il = 0; il < TI; ++il) acc[il] = g0;
        #pragma unroll
        for (int e = 0; e < 32; ++e) {
            float we = grow[e];
            #pragma unroll
            for (int il = 0; il < TI; ++il)
                acc[il] = fmaf(we, sX[(il << 5) + e], acc[il]);
        }
        #pragma unroll
        for (int il = 0; il < TI; ++il) sUT[(il << 8) + tid] = acc[il];
        sC[tid] = We1[tid * 65 + 64];
        sW2[tid] = We2[tid];
    }
    __syncthreads();

    // phase 3: scores; wave wv owns h-quarter, lane = j, all 4 i's
    const int wv = tid >> 6, lane = tid & 63;
    {
        const int hc0 = wv << 4;
        const float4* wT4 = (const float4*)w + (size_t)(b * 64) * Ny;
        const float4* c4p = (const float4*)sC;
        const float4* p4p = (const float4*)sW2;
        if (Ny == 64) {
            float dv[TI];
            #pragma unroll
            for (int il = 0; il < TI; ++il) dv[il] = sDis[(il << 7) + lane];
            float acc[TI] = {0.f, 0.f, 0.f, 0.f};
            #pragma unroll
            for (int t = 0; t < 16; ++t) {
                int hc = hc0 + t;
                float4 w4 = wT4[((size_t)hc << 6) + lane];
                float4 c4 = c4p[hc], p4 = p4p[hc];
                #pragma unroll
                for (int il = 0; il < TI; ++il) {
                    float4 u4 = ((const float4*)(sUT + (il << 8)))[hc];
                    acc[il] = fmaf(p4.x, fmaxf(fmaf(c4.x, dv[il], u4.x + w4.x), 0.f), acc[il]);
                    acc[il] = fmaf(p4.y, fmaxf(fmaf(c4.y, dv[il], u4.y + w4.y), 0.f), acc[il]);
                    acc[il] = fmaf(p4.z, fmaxf(fmaf(c4.z, dv[il], u4.z + w4.z), 0.f), acc[il]);
                    acc[il] = fmaf(p4.w, fmaxf(fmaf(c4.w, dv[il], u4.w + w4.w), 0.f), acc[il]);
                }
            }
            #pragma unroll
            for (int il = 0; il < TI; ++il)
                sPR[(wv << 9) + (il << 7) + lane] = acc[il];
        } else {
            float dv0[TI], dv1[TI];
            #pragma unroll
            for (int il = 0; il < TI; ++il) {
                dv0[il] = sDis[(il << 7) + lane];
                dv1[il] = sDis[(il << 7) + 64 + lane];
            }
            float acc0[TI] = {0.f, 0.f, 0.f, 0.f};
            float acc1[TI] = {0.f, 0.f, 0.f, 0.f};
            #pragma unroll
            for (int t = 0; t < 16; ++t) {
                int hc = hc0 + t;
                float4 wa = wT4[((size_t)hc << 7) + lane];
                float4 wb = wT4[((size_t)hc << 7) + 64 + lane];
                float4 c4 = c4p[hc], p4 = p4p[hc];
                #pragma unroll
                for (int il = 0; il < TI; ++il) {
                    float4 u4 = ((const float4*)(sUT + (il << 8)))[hc];
                    acc0[il] = fmaf(p4.x, fmaxf(fmaf(c4.x, dv0[il], u4.x + wa.x), 0.f), acc0[il]);
                    acc0[il] = fmaf(p4.y, fmaxf(fmaf(c4.y, dv0[il], u4.y + wa.y), 0.f), acc0[il]);
                    acc0[il] = fmaf(p4.z, fmaxf(fmaf(c4.z, dv0[il], u4.z + wa.z), 0.f), acc0[il]);
                    acc0[il] = fmaf(p4.w, fmaxf(fmaf(c4.w, dv0[il], u4.w + wa.w), 0.f), acc0[il]);
                    acc1[il] = fmaf(p4.x, fmaxf(fmaf(c4.x, dv1[il], u4.x + wb.x), 0.f), acc1[il]);
                    acc1[il] = fmaf(p4.y, fmaxf(fmaf(c4.y, dv1[il], u4.y + wb.y), 0.f), acc1[il]);
                    acc1[il] = fmaf(p4.z, fmaxf(fmaf(c4.z, dv1[il], u4.z + wb.z), 0.f), acc1[il]);
                    acc1[il] = fmaf(p4.w, fmaxf(fmaf(c4.w, dv1[il], u4.w + wb.w), 0.f), acc1[il]);
                }
            }
            #pragma unroll
            for (int il = 0; il < TI; ++il) {
                sPR[(wv << 9) + (il << 7) + lane] = acc0[il];
                sPR[(wv << 9) + (il << 7) + 64 + lane] = acc1[il];
            }
        }
    }
    __syncthreads();

    // phase 4 (merged reduce + softmax): wave wv handles row wv
    {
        const int base = (wv << 7) + lane;
        float v0 = sPR[base] + sPR[512 + base] + sPR[1024 + base] + sPR[1536 + base];
        float v1 = -1e30f;
        if (Ny == 128) {
            const int b2 = base + 64;
            v1 = sPR[b2] + sPR[512 + b2] + sPR[1024 + b2] + sPR[1536 + b2];
        }
        float m = fmaxf(v0, v1);
        #pragma unroll
        for (int msk = 32; msk; msk >>= 1) m = fmaxf(m, __shfl_xor(m, msk));
        float e0 = __expf(v0 - m);
        float e1 = (Ny == 128) ? __expf(v1 - m) : 0.f;
        float s = e0 + e1;
        #pragma unroll
        for (int msk = 32; msk; msk >>= 1) s += __shfl_xor(s, msk);
        float inv = 1.0f / s;
        e0 *= inv; e1 *= inv;
        sS[base] = e0;
        if (Ny == 128) sS[base + 64] = e1;
        if (ep) {
            float* erow = ep + ((size_t)(b * Nx + i0 + wv)) * Ny;
            erow[lane] = e0;
            if (Ny == 128) erow[64 + lane] = e1;
        }
    }

    // phase 5: agg = e @ yv (global yv, L2-resident; coalesced 2 rows/iter)
    {
        const int dd = lane & 31, jg = lane >> 5;
        const float* yvg = yv + ((size_t)(b * Ny) << 5);
        float p = 0.f;
        #pragma unroll 8
        for (int j = jg; j < Ny; j += 2)
            p = fmaf(sS[(wv << 7) + j], yvg[(j << 5) + dd], p);
        p += __shfl_xor(p, 32);
        if (jg == 0) sAgg[(wv << 5) + dd] = p;
    }
    __syncthreads();

    // phase 7: node-MLP hidden (T overlays u)
    {
        const float4* w14 = (const float4*)(Wn1 + (tid << 6));
        const float b1 = bn1[tid];
        float acc[TI];
        #pragma unroll
        for (int il = 0; il < TI; ++il) acc[il] = b1;
        #pragma unroll
        for (int k = 0; k < 8; ++k) {
            float4 wa = w14[k];
            #pragma unroll
            for (int il = 0; il < TI; ++il)
                acc[il] += dot4(wa, ((const float4*)(sX + (il << 5)))[k]);
        }
        #pragma unroll
        for (int k = 0; k < 8; ++k) {
            float4 wb = w14[8 + k];
            #pragma unroll
            for (int il = 0; il < TI; ++il)
                acc[il] += dot4(wb, ((const float4*)(sAgg + (il << 5)))[k]);
        }
        __syncthreads();
        #pragma unroll
        for (int il = 0; il < TI; ++il) sUT[(il << 8) + tid] = fmaxf(acc[il], 0.f);
    }
    __syncthreads();

    // phase 8: out = x + T @ Wn2^T + bn2
    {
        const int hg = tid >> 5, dd = tid & 31;
        const float4* w24 = (const float4*)(Wn2 + (dd << 8) + (hg << 5));
        float4 w2r[8];
        #pragma unroll
        for (int k = 0; k < 8; ++k) w2r[k] = w24[k];
        float p[TI] = {0.f, 0.f, 0.f, 0.f};
        #pragma unroll
        for (int k = 0; k < 8; ++k) {
            #pragma unroll
            for (int il = 0; il < TI; ++il)
                p[il] += dot4(w2r[k], ((const float4*)(sUT + (il << 8) + (hg << 5)))[k]);
        }
        #pragma unroll
        for (int il = 0; il < TI; ++il) sPR[(hg << 7) + (il << 5) + dd] = p[il];
    }
    __syncthreads();
    if (tid < 128) {
        int il = tid >> 5, dd = tid & 31;
        float a = bn2[dd] + sX[tid];
        #pragma unroll
        for (int hg = 0; hg < 8; ++hg) a += sPR[(hg << 7) + tid];
        outp[((size_t)(b * Nx + i0 + il)) * 32 + dd] = a;
        if (wPre) sQ[tid] = a;     // keep out rows for tail
    }

    // ---- H-fused pre tail (stage-6 blocks): w/yv for the next stage ----
    if (wPre) {
        __syncthreads();
        if (tid < 128) {           // yv = Wv out + bv
            int il = tid >> 5, dd = tid & 31;
            const float4* wm4 = (const float4*)(Wv + (dd << 5));
            const float4* orow = (const float4*)(sQ + (il << 5));
            float a = bv[dd];
            #pragma unroll
            for (int k = 0; k < 8; ++k) a += dot4(wm4[k], orow[k]);
            yvPre[(((size_t)(b * Nx + i0 + il)) << 5) + dd] = a;
        }
        {                          // w = H out + hb (no yk round-trip)
            const float* hrow = Hm + (tid << 5);
            const float hb0 = hbvec[tid];
            float acc[4];
            #pragma unroll
            for (int il = 0; il < 4; ++il) acc[il] = hb0;
            #pragma unroll
            for (int e = 0; e < 32; ++e) {
                float we = hrow[e];
                #pragma unroll
                for (int il = 0; il < 4; ++il)
                    acc[il] = fmaf(we, sQ[(il << 5) + e], acc[il]);
            }
            float* wbase = wPre + (((size_t)b * 64 + (tid >> 2)) * Nx + i0) * 4 + (tid & 3);
            #pragma unroll
            for (int il = 0; il < 4; ++il)
                wbase[il << 2] = acc[il];
        }
    }
}

// ---------------------------------------------------------------------------
// inter_fused: ONE ordinary launch (graph-capture-safe) for stages C and D,
// synchronized by per-batch device-scope atomic flags (Guideline 16 pattern).
// Blocks [0,1280): stage C = inter5 (256 tasks) + inter6 (1024 tasks, pre7
// tail -> w7/yv7), segment-balanced XCD swizzle. Each task releases
// flag[batch] (threadfence + atomicAdd). Blocks [1280,1536): stage D task t;
// tid0 spins until flag[b]==40 (8 A + 32 B producers), acquire, then runs.
// Batch b's A/B/D tasks all map to XCD b>>2 -> flag + tiles stay in one L2.
// LDS 19,968B -> 8 blocks/CU -> capacity 2048 >= 1536: all blocks resident,
// spin-wait cannot deadlock (capacity argument, no dispatch-order assumption).
// ---------------------------------------------------------------------------
__global__ __launch_bounds__(256, 8) void inter_fused_kernel(
    const float* __restrict__ xA, const float* __restrict__ wA, const float* __restrict__ yvA,
    const float* __restrict__ disA, float* __restrict__ outA,
    const float* __restrict__ xB, const float* __restrict__ wB, const float* __restrict__ yvB,
    const float* __restrict__ disB, float* __restrict__ outB,
    float* __restrict__ w7p, float* __restrict__ yv7p,
    const float* __restrict__ disD, float* __restrict__ outD, float* __restrict__ eD,
    const float* __restrict__ Gm, const float* __restrict__ gvec,
    const float* __restrict__ Hm, const float* __restrict__ hbvec,
    const float* __restrict__ Wv, const float* __restrict__ bv,
    const float* __restrict__ We1, const float* __restrict__ We2,
    const float* __restrict__ Wn1, const float* __restrict__ bn1,
    const float* __restrict__ Wn2, const float* __restrict__ bn2,
    unsigned* __restrict__ flags)
{
    __shared__ __align__(16) float sX[128];
    __shared__ __align__(16) float sQ[128];
    __shared__ __align__(16) float sAgg[128];
    __shared__ __align__(16) float sDis[512];
    __shared__ __align__(16) float sC[256];
    __shared__ __align__(16) float sW2[256];
    __shared__ __align__(16) float sS[512];
    __shared__ __align__(16) float sUT[1024];
    __shared__ __align__(16) float sPR[2048];

    const int blk = (int)blockIdx.x, tid = threadIdx.x;

    if (blk < 1280) {
        // ---- stage C: segment-balanced XCD swizzle over 256 A + 1024 B
        const int xcd = blk & 7, slot = blk >> 3;   // slot 0..159
        int bb;
        if (slot < 32) {
            const int t = (xcd << 5) + slot;        // A task [0,256)
            bb = t >> 3;
            inter_body(xA, NRr, wA, yvA, NHh, disA, outA,
                       nullptr, nullptr, nullptr, t,
                       Gm, gvec, Hm, hbvec, Wv, bv, We1, We2,
                       Wn1, bn1, Wn2, bn2,
                       sX, sQ, sAgg, sDis, sC, sW2, sS, sUT, sPR);
        } else {
            const int t = (xcd << 7) + (slot - 32); // B task [0,1024)
            bb = t >> 5;
            inter_body(xB, NFf, wB, yvB, NFHh, disB, outB,
                       nullptr, w7p, yv7p, t,
                       Gm, gvec, Hm, hbvec, Wv, bv, We1, We2,
                       Wn1, bn1, Wn2, bn2,
                       sX, sQ, sAgg, sDis, sC, sW2, sS, sUT, sPR);
        }
        // release: make this block's writes device-visible, then signal
        __threadfence();
        __syncthreads();
        if (tid == 0) atomicAdd(&flags[bb], 1u);
    } else {
        // ---- stage D: task t, waits for its batch's 40 producers
        const int i = blk - 1280;                   // [0,256)
        const int t = ((i & 7) << 5) + (i >> 3);    // same per-XCD batching
        const int bb = t >> 3;
        if (tid == 0) {
            while (atomicAdd(&flags[bb], 0u) < 40u)
                __builtin_amdgcn_s_sleep(2);
        }
        __syncthreads();
        __threadfence();   // acquire: see producers' plain stores
        inter_body(outA /*robot2*/, NRr, w7p, yv7p, NFf, disD, outD,
                   eD, nullptr, nullptr, t,
                   Gm, gvec, Hm, hbvec, Wv, bv, We1, We2,
                   Wn1, bn1, Wn2, bn2,
                   sX, sQ, sAgg, sDis, sC, sW2, sS, sUT, sPR);
    }
}

// ---------------------------------------------------------------------------
extern "C" void kernel_launch(void* const* d_in, const int* in_sizes, int n_in,
                              void* d_out, int out_size, void* d_ws, size_t ws_size,
                              hipStream_t stream) {
    const float* robot          = (const float*)d_in[0];
    const float* frontier       = (const float*)d_in[1];
    const float* rh             = (const float*)d_in[2];
    const float* fh             = (const float*)d_in[3];
    const float* robot_frontier = (const float*)d_in[4];
    const float* robot_past     = (const float*)d_in[5];
    const float* frontier_past  = (const float*)d_in[6];
    const float* Wq  = (const float*)d_in[7];  const float* bq  = (const float*)d_in[8];
    const float* Wk  = (const float*)d_in[9];  const float* bk  = (const float*)d_in[10];
    const float* Wv  = (const float*)d_in[11]; const float* bv  = (const float*)d_in[12];
    const float* Wn1 = (const float*)d_in[13]; const float* bn1 = (const float*)d_in[14];
    const float* Wn2 = (const float*)d_in[15]; const float* bn2 = (const float*)d_in[16];
    const float* We1 = (const float*)d_in[17]; const float* be1 = (const float*)d_in[18];
    const float* We2 = (const float*)d_in[19];

    float* out = (float*)d_out;
    float* out_robot    = out;            // 32*32*32   = 32768
    float* out_frontier = out + 32768;    // 32*128*32  = 131072
    float* out_rh       = out + 163840;   // 32*64*32   = 65536
    float* out_fh       = out + 229376;   // 32*64*32   = 65536
    float* out_edge     = out + 294912;   // 32*32*128  = 131072

    float* W = (float*)d_ws;
    float* robot1 = W;                 // 32768
    float* robot2 = W + 32768;         // 32768
    float* nf     = W + 65536;         // 131072
    float* w5     = W + 196608;        // 524288 (wT layout)
    float* yv5    = W + 720896;        // 65536
    float* w6     = W + 786432;        // 524288 (wT layout)
    float* yv6    = W + 1310720;       // 65536
    float* w7     = W + 1376256;       // 1048576 (wT layout)
    float* yv7    = W + 2424832;       // 131072 -> 2555904
    float* Gm     = W + 2555904;       // 8192
    float* gvec   = W + 2564096;       // 256
    float* Hm     = W + 2564352;       // 8192
    float* hbvec  = W + 2572544;       // 256 -> ends 2572800
    unsigned* flags = (unsigned*)(W + 2572800);  // 32 uints

    // A: four intra-attentions + merged pre_y tails + G/H blocks (576+32);
    // block 576 also zeroes the flags for launch B.
    intra_kernel<<<608, 256, 0, stream>>>(robot, frontier, rh, fh,
        Wq, bq, Wk, bk, Wv, bv, Wn1, bn1, Wn2, bn2, We1, be1,
        robot1, out_frontier, out_rh, out_fh,
        w5, yv5, w6, yv6, Gm, gvec, Hm, hbvec, flags);

    // B: fused inter (stage C: inter5+inter6 -> flags; stage D: inter7 spins)
    inter_fused_kernel<<<1536, 256, 0, stream>>>(
        robot1, w5, yv5, robot_past, robot2,
        out_frontier, w6, yv6, frontier_past, nf,
        w7, yv7,
        robot_frontier, out_robot, out_edge,
        Gm, gvec, Hm, hbvec, Wv, bv, We1, We2, Wn1, bn1, Wn2, bn2,
        flags);
}

// Round 9
// 395.110 us; speedup vs baseline: 1.0292x; 1.0292x over previous
//
#include <hip/hip_runtime.h>

#define BATCH 32
#define NRr 32
#define NFf 128
#define NHh 64
#define NFHh 64
#define TI 4

__device__ __forceinline__ float dot4(float4 a, float4 b) {
    return fmaf(a.x, b.x, fmaf(a.y, b.y, fmaf(a.z, b.z, a.w * b.w)));
}

// ---------------------------------------------------------------------------
// intra v14 (R6): CH=16, balanced XCD swizzle, merged pre_y tail on rh/fh
// blocks, G/H weight blocks at 576..607. Block 576 additionally zeroes the
// 32 per-batch flags used by the fused inter launch (same stream -> ordered).
// ---------------------------------------------------------------------------
__global__ __launch_bounds__(256, 4) void intra_kernel(
    const float* __restrict__ robot, const float* __restrict__ frontier,
    const float* __restrict__ rhist, const float* __restrict__ fhist,
    const float* __restrict__ Wq, const float* __restrict__ bq,
    const float* __restrict__ Wk, const float* __restrict__ bk,
    const float* __restrict__ Wv, const float* __restrict__ bv,
    const float* __restrict__ Wn1, const float* __restrict__ bn1,
    const float* __restrict__ Wn2, const float* __restrict__ bn2,
    const float* __restrict__ We1, const float* __restrict__ be1,
    float* __restrict__ o_robot, float* __restrict__ o_frontier,
    float* __restrict__ o_rh, float* __restrict__ o_fh,
    float* __restrict__ w5, float* __restrict__ yv5,
    float* __restrict__ w6, float* __restrict__ yv6,
    float* __restrict__ Gm, float* __restrict__ gvec,
    float* __restrict__ Hm, float* __restrict__ hbvec,
    unsigned* __restrict__ flags)
{
    __shared__ __align__(16) float sXc[512];    // chunk rows [16][32]
    __shared__ __align__(16) float sQ[512];     // q, then z, then out rows
    __shared__ __align__(16) float sQK[512];    // Wk^T q rows, then yk rows
    __shared__ __align__(16) float sAgg[512];   // agg rows
    __shared__ __align__(16) float sBig[6240];
    float* sS  = sBig;           // scores [16][P], P = N+4   (<=2112)
    float* sXT = sBig + 2112;    // x^T [32][P2], P2 = N+1    (<=4128)
    float* sT  = sBig;           // T [16][256] overlays after agg (4096)

    const int rawblk = blockIdx.x, tid = threadIdx.x;

    if (rawblk >= 576) {   // G/H fused-matrix blocks (weights only)
        if (rawblk == 576 && tid < 32) flags[tid] = 0u;   // reset flags
        const int hr = ((rawblk - 576) << 3) + (tid >> 5), e = tid & 31;
        const float* w1q = We1 + hr * 65;
        const float* w1k = w1q + 32;
        float aG = 0.f, aH = 0.f;
        #pragma unroll
        for (int d2 = 0; d2 < 32; ++d2) {
            aG = fmaf(w1q[d2], Wq[d2 * 32 + e], aG);
            aH = fmaf(w1k[d2], Wk[d2 * 32 + e], aH);
        }
        Gm[(hr << 5) + e] = aG;
        Hm[(hr << 5) + e] = aH;
        if (e == 0) {
            float ag = be1[hr], ahb = 0.f;
            #pragma unroll
            for (int d2 = 0; d2 < 32; ++d2) {
                ag  = fmaf(w1q[d2], bq[d2], ag);
                ahb = fmaf(w1k[d2], bk[d2], ahb);
            }
            gvec[hr] = ag;
            hbvec[hr] = ahb;
        }
        return;
    }

    // segment-balanced XCD swizzle: each XCD gets 8 robot / 32 frontier /
    // 16 rh / 16 fh slots, whole batches contiguous per XCD.
    const int xcd = rawblk & 7, slot = rawblk >> 3; // 0..71
    int blk;
    if (slot < 8)       blk = (xcd << 3) + slot;                // [0,64)
    else if (slot < 40) blk = 64  + (xcd << 5) + (slot - 8);    // [64,320)
    else if (slot < 56) blk = 320 + (xcd << 4) + (slot - 40);   // [320,448)
    else                blk = 448 + (xcd << 4) + (slot - 56);   // [448,576)

    const float* xin; float* xout; int N, lgN, b, chunk;
    float* wPre = nullptr; float* yvPre = nullptr;
    if (blk < 64)       { xin=robot;    xout=o_robot;    N=32;  lgN=5; b=blk>>1;       chunk=blk&1; }
    else if (blk < 320) { xin=frontier; xout=o_frontier; N=128; lgN=7; b=(blk-64)>>3;  chunk=(blk-64)&7; }
    else if (blk < 448) { xin=rhist;    xout=o_rh;       N=64;  lgN=6; b=(blk-320)>>2; chunk=(blk-320)&3; wPre=w5; yvPre=yv5; }
    else                { xin=fhist;    xout=o_fh;       N=64;  lgN=6; b=(blk-448)>>2; chunk=(blk-448)&3; wPre=w6; yvPre=yv6; }

    const int P = N + 4, P2 = N + 1;
    const float* xb = xin + (size_t)b * N * 32;
    const int r0 = chunk << 4;           // CH = 16
    const int d = tid & 31;
    const int rloc = tid >> 5;           // 0..7

    // stage chunk rows + full x^T
    sXc[tid] = xb[(r0 << 5) + tid];
    sXc[tid + 256] = xb[(r0 << 5) + tid + 256];
    for (int idx = tid; idx < (N << 5); idx += 256) {
        int j = idx >> 5, d2 = idx & 31;
        sXT[d2 * P2 + j] = xb[idx];
    }
    __syncthreads();

    // q[rr][d], rr in {rloc, rloc+8}
    {
        const float4* wq4 = (const float4*)(Wq + (d << 5));
        float4 wq[8];
        #pragma unroll
        for (int k = 0; k < 8; ++k) wq[k] = wq4[k];
        const float bqd = bq[d];
        #pragma unroll
        for (int p = 0; p < 2; ++p) {
            int rr = rloc + (p << 3);
            const float4* xr = (const float4*)(sXc + (rr << 5));
            float a = bqd;
            #pragma unroll
            for (int k = 0; k < 8; ++k) a += dot4(wq[k], xr[k]);
            sQ[(rr << 5) + d] = a;
        }
    }
    __syncthreads();

    // qk[rr][e] = sum_dd Wk[dd][e] * q[rr][dd]
    {
        #pragma unroll
        for (int p = 0; p < 2; ++p) {
            int rr = rloc + (p << 3);
            const float* qr = sQ + (rr << 5);
            float a = 0.f;
            #pragma unroll
            for (int dd2 = 0; dd2 < 32; ++dd2)
                a = fmaf(Wk[dd2 * 32 + d], qr[dd2], a);
            sQK[(rr << 5) + d] = a;
        }
    }
    __syncthreads();

    // scores [16][N]
    for (int idx = tid; idx < (16 << lgN); idx += 256) {
        int r = idx >> lgN, j = idx & (N - 1);
        const float* qr = sQK + (r << 5);
        float a = 0.f;
        #pragma unroll
        for (int e = 0; e < 32; ++e) a = fmaf(qr[e], sXT[e * P2 + j], a);
        sS[r * P + j] = a;
    }
    __syncthreads();

    // softmax: rows {rloc, rloc+8}, 32 lanes each
    {
        #pragma unroll
        for (int p = 0; p < 2; ++p) {
            int rr = rloc + (p << 3);
            float* row = sS + rr * P;
            float m = -1e30f;
            for (int j = d; j < N; j += 32) m = fmaxf(m, row[j]);
            #pragma unroll
            for (int msk = 16; msk; msk >>= 1) m = fmaxf(m, __shfl_xor(m, msk));
            float s = 0.f;
            for (int j = d; j < N; j += 32) { float ev = __expf(row[j] - m); row[j] = ev; s += ev; }
            #pragma unroll
            for (int msk = 16; msk; msk >>= 1) s += __shfl_xor(s, msk);
            float inv = 1.0f / s;
            for (int j = d; j < N; j += 32) row[j] *= inv;
        }
    }
    __syncthreads();

    // z[rr][d] = e_rr @ x[:, d]  (4 accumulators break the serial chain)
    {
        #pragma unroll
        for (int p = 0; p < 2; ++p) {
            int rr = rloc + (p << 3);
            const float* er = sS + rr * P;
            const float* xtr = sXT + d * P2;
            float a0 = 0.f, a1 = 0.f, a2 = 0.f, a3 = 0.f;
            for (int j = 0; j < N; j += 4) {
                a0 = fmaf(er[j],     xtr[j],     a0);
                a1 = fmaf(er[j + 1], xtr[j + 1], a1);
                a2 = fmaf(er[j + 2], xtr[j + 2], a2);
                a3 = fmaf(er[j + 3], xtr[j + 3], a3);
            }
            sQ[(rr << 5) + d] = (a0 + a1) + (a2 + a3);
        }
    }
    __syncthreads();

    // agg[rr][d] = Wv[d] . z[rr] + bv[d]
    {
        const float4* wv4 = (const float4*)(Wv + (d << 5));
        float4 wv[8];
        #pragma unroll
        for (int k = 0; k < 8; ++k) wv[k] = wv4[k];
        const float bvd = bv[d];
        #pragma unroll
        for (int p = 0; p < 2; ++p) {
            int rr = rloc + (p << 3);
            const float4* zr = (const float4*)(sQ + (rr << 5));
            float a = bvd;
            #pragma unroll
            for (int k = 0; k < 8; ++k) a += dot4(wv[k], zr[k]);
            sAgg[(rr << 5) + d] = a;
        }
    }
    __syncthreads();

    // node-MLP hidden: thread owns hid h=tid, loops 16 rows (w1r amortized)
    {
        const float4* w14 = (const float4*)(Wn1 + (tid << 6));
        float4 w1r[16];
        #pragma unroll
        for (int k = 0; k < 16; ++k) w1r[k] = w14[k];
        const float b1 = bn1[tid];
        #pragma unroll
        for (int r = 0; r < 16; ++r) {
            const float4* xr = (const float4*)(sXc + (r << 5));
            const float4* ar = (const float4*)(sAgg + (r << 5));
            float a = b1;
            #pragma unroll
            for (int k = 0; k < 8; ++k) a += dot4(w1r[k], xr[k]);
            #pragma unroll
            for (int k = 0; k < 8; ++k) a += dot4(w1r[8 + k], ar[k]);
            sT[(r << 8) + tid] = fmaxf(a, 0.f);
        }
    }
    __syncthreads();

    // out: thread (rg,d) does rows rg and rg+8 (w2r amortized over 2 rows)
    {
        const int rg = tid >> 5;
        float acc0 = 0.f, acc1 = 0.f;
        #pragma unroll
        for (int hc = 0; hc < 4; ++hc) {
            const float4* w24 = (const float4*)(Wn2 + (d << 8) + (hc << 6));
            float4 w2r[16];
            #pragma unroll
            for (int k = 0; k < 16; ++k) w2r[k] = w24[k];
            const float4* t0 = (const float4*)(sT + (rg << 8) + (hc << 6));
            const float4* t1 = (const float4*)(sT + ((rg + 8) << 8) + (hc << 6));
            #pragma unroll
            for (int k = 0; k < 16; ++k) {
                acc0 += dot4(w2r[k], t0[k]);
                acc1 += dot4(w2r[k], t1[k]);
            }
        }
        const float b2 = bn2[d];
        const size_t base = ((size_t)b * N) << 5;
        float o0 = sXc[(rg << 5) + d] + b2 + acc0;
        float o1 = sXc[((rg + 8) << 5) + d] + b2 + acc1;
        xout[base + ((r0 + rg) << 5) + d]     = o0;
        xout[base + ((r0 + rg + 8) << 5) + d] = o1;
        if (wPre) {                      // keep out rows for the pre tail
            sQ[(rg << 5) + d] = o0;
            sQ[((rg + 8) << 5) + d] = o1;
        }
    }

    // ---- merged pre_y tail (rh/fh blocks): w/yv for the inter launches ----
    if (wPre) {
        __syncthreads();
        // yk[rr] = Wk*out+bk -> sQK ; yv[rr] = Wv*out+bv -> global
        {
            const float4* wk4 = (const float4*)(Wk + (d << 5));
            const float4* wv4 = (const float4*)(Wv + (d << 5));
            const float bkd = bk[d], bvd = bv[d];
            #pragma unroll
            for (int p = 0; p < 2; ++p) {
                int rr = rloc + (p << 3);
                const float4* orow = (const float4*)(sQ + (rr << 5));
                float aK = bkd, aV = bvd;
                #pragma unroll
                for (int k = 0; k < 8; ++k) {
                    float4 o = orow[k];
                    aK += dot4(wk4[k], o);
                    aV += dot4(wv4[k], o);
                }
                sQK[(rr << 5) + d] = aK;
                yvPre[((size_t)(b * N + r0 + rr) << 5) + d] = aV;
            }
        }
        __syncthreads();
        // w[h][j] = We1[h,32:64] . yk[j]   (h = tid, j = r0..r0+15)
        {
            const float* w1 = We1 + tid * 65 + 32;
            float acc[16];
            #pragma unroll
            for (int jl = 0; jl < 16; ++jl) acc[jl] = 0.f;
            #pragma unroll
            for (int e = 0; e < 32; ++e) {
                float we = w1[e];
                #pragma unroll
                for (int jl = 0; jl < 16; ++jl)
                    acc[jl] = fmaf(we, sQK[(jl << 5) + e], acc[jl]);
            }
            float* wbase = wPre + (((size_t)b * 64 + (tid >> 2)) * N + r0) * 4 + (tid & 3);
            #pragma unroll
            for (int jl = 0; jl < 16; ++jl)
                wbase[jl << 2] = acc[jl];
        }
    }
}

// ---------------------------------------------------------------------------
// inter body (R6 inter v12, factored): one 4-row x-tile vs a y-side.
// wT layout: ((b*64+h/4)*Ny + j)*4 + h%4.
// ---------------------------------------------------------------------------
__device__ __forceinline__ void inter_body(
    const float* __restrict__ x, int Nx, const float* __restrict__ w,
    const float* __restrict__ yv, int Ny, const float* __restrict__ dis,
    float* __restrict__ outp, float* __restrict__ ep,
    float* __restrict__ wPre, float* __restrict__ yvPre, int idx,
    const float* __restrict__ Gm, const float* __restrict__ gvec,
    const float* __restrict__ Hm, const float* __restrict__ hbvec,
    const float* __restrict__ Wv, const float* __restrict__ bv,
    const float* __restrict__ We1, const float* __restrict__ We2,
    const float* __restrict__ Wn1, const float* __restrict__ bn1,
    const float* __restrict__ Wn2, const float* __restrict__ bn2,
    float* sX, float* sQ, float* sAgg, float* sDis, float* sC, float* sW2,
    float* sS, float* sUT, float* sPR)
{
    const int tid = threadIdx.x;
    const int lgNy = (Ny == 128) ? 7 : 6;
    const int tiles = Nx >> 2;
    const int b = idx / tiles, i0 = (idx - b * tiles) << 2;
    const float* xrow = x + ((size_t)(b * Nx + i0)) * 32;

    // phase 0: stage x, dis (yv stays in global/L2)
    if (tid < 128) sX[tid] = xrow[tid];
    if (tid < Ny) {
        int il = tid >> (lgNy - 2), jq = tid & ((Ny >> 2) - 1);
        ((float4*)sDis)[(il << 5) + jq] =
            ((const float4*)(dis + ((size_t)(b * Nx + i0 + il)) * Ny))[jq];
    }
    __syncthreads();

    // phase 2 (G-fused): u = G x + g ; c, w2
    {
        const float* grow = Gm + (tid << 5);
        const float g0 = gvec[tid];
        float acc[TI];
        #pragma unroll
        for (int il = 0; il < TI; ++il) acc[il] = g0;
        #pragma unroll
        for (int e = 0; e < 32; ++e) {
            float we = grow[e];
            #pragma unroll
            for (int il = 0; il < TI; ++il)
                acc[il] = fmaf(we, sX[(il << 5) + e], acc[il]);
        }
        #pragma unroll
        for (int il = 0; il < TI; ++il) sUT[(il << 8) + tid] = acc[il];
        sC[tid] = We1[tid * 65 + 64];
        sW2[tid] = We2[tid];
    }
    __syncthreads();

    // phase 3: scores; wave wv owns h-quarter, lane = j, all 4 i's
    const int wv = tid >> 6, lane = tid & 63;
    {
        const int hc0 = wv << 4;
        const float4* wT4 = (const float4*)w + (size_t)(b * 64) * Ny;
        const float4* c4p = (const float4*)sC;
        const float4* p4p = (const float4*)sW2;
        if (Ny == 64) {
            float dv[TI];
            #pragma unroll
            for (int il = 0; il < TI; ++il) dv[il] = sDis[(il << 7) + lane];
            float acc[TI] = {0.f, 0.f, 0.f, 0.f};
            #pragma unroll
            for (int t = 0; t < 16; ++t) {
                int hc = hc0 + t;
                float4 w4 = wT4[((size_t)hc << 6) + lane];
                float4 c4 = c4p[hc], p4 = p4p[hc];
                #pragma unroll
                for (int il = 0; il < TI; ++il) {
                    float4 u4 = ((const float4*)(sUT + (il << 8)))[hc];
                    acc[il] = fmaf(p4.x, fmaxf(fmaf(c4.x, dv[il], u4.x + w4.x), 0.f), acc[il]);
                    acc[il] = fmaf(p4.y, fmaxf(fmaf(c4.y, dv[il], u4.y + w4.y), 0.f), acc[il]);
                    acc[il] = fmaf(p4.z, fmaxf(fmaf(c4.z, dv[il], u4.z + w4.z), 0.f), acc[il]);
                    acc[il] = fmaf(p4.w, fmaxf(fmaf(c4.w, dv[il], u4.w + w4.w), 0.f), acc[il]);
                }
            }
            #pragma unroll
            for (int il = 0; il < TI; ++il)
                sPR[(wv << 9) + (il << 7) + lane] = acc[il];
        } else {
            float dv0[TI], dv1[TI];
            #pragma unroll
            for (int il = 0; il < TI; ++il) {
                dv0[il] = sDis[(il << 7) + lane];
                dv1[il] = sDis[(il << 7) + 64 + lane];
            }
            float acc0[TI] = {0.f, 0.f, 0.f, 0.f};
            float acc1[TI] = {0.f, 0.f, 0.f, 0.f};
            #pragma unroll
            for (int t = 0; t < 16; ++t) {
                int hc = hc0 + t;
                float4 wa = wT4[((size_t)hc << 7) + lane];
                float4 wb = wT4[((size_t)hc << 7) + 64 + lane];
                float4 c4 = c4p[hc], p4 = p4p[hc];
                #pragma unroll
                for (int il = 0; il < TI; ++il) {
                    float4 u4 = ((const float4*)(sUT + (il << 8)))[hc];
                    acc0[il] = fmaf(p4.x, fmaxf(fmaf(c4.x, dv0[il], u4.x + wa.x), 0.f), acc0[il]);
                    acc0[il] = fmaf(p4.y, fmaxf(fmaf(c4.y, dv0[il], u4.y + wa.y), 0.f), acc0[il]);
                    acc0[il] = fmaf(p4.z, fmaxf(fmaf(c4.z, dv0[il], u4.z + wa.z), 0.f), acc0[il]);
                    acc0[il] = fmaf(p4.w, fmaxf(fmaf(c4.w, dv0[il], u4.w + wa.w), 0.f), acc0[il]);
                    acc1[il] = fmaf(p4.x, fmaxf(fmaf(c4.x, dv1[il], u4.x + wb.x), 0.f), acc1[il]);
                    acc1[il] = fmaf(p4.y, fmaxf(fmaf(c4.y, dv1[il], u4.y + wb.y), 0.f), acc1[il]);
                    acc1[il] = fmaf(p4.z, fmaxf(fmaf(c4.z, dv1[il], u4.z + wb.z), 0.f), acc1[il]);
                    acc1[il] = fmaf(p4.w, fmaxf(fmaf(c4.w, dv1[il], u4.w + wb.w), 0.f), acc1[il]);
                }
            }
            #pragma unroll
            for (int il = 0; il < TI; ++il) {
                sPR[(wv << 9) + (il << 7) + lane] = acc0[il];
                sPR[(wv << 9) + (il << 7) + 64 + lane] = acc1[il];
            }
        }
    }
    __syncthreads();

    // phase 4 (merged reduce + softmax): wave wv handles row wv
    {
        const int base = (wv << 7) + lane;
        float v0 = sPR[base] + sPR[512 + base] + sPR[1024 + base] + sPR[1536 + base];
        float v1 = -1e30f;
        if (Ny == 128) {
            const int b2 = base + 64;
            v1 = sPR[b2] + sPR[512 + b2] + sPR[1024 + b2] + sPR[1536 + b2];
        }
        float m = fmaxf(v0, v1);
        #pragma unroll
        for (int msk = 32; msk; msk >>= 1) m = fmaxf(m, __shfl_xor(m, msk));
        float e0 = __expf(v0 - m);
        float e1 = (Ny == 128) ? __expf(v1 - m) : 0.f;
        float s = e0 + e1;
        #pragma unroll
        for (int msk = 32; msk; msk >>= 1) s += __shfl_xor(s, msk);
        float inv = 1.0f / s;
        e0 *= inv; e1 *= inv;
        sS[base] = e0;
        if (Ny == 128) sS[base + 64] = e1;
        if (ep) {
            float* erow = ep + ((size_t)(b * Nx + i0 + wv)) * Ny;
            erow[lane] = e0;
            if (Ny == 128) erow[64 + lane] = e1;
        }
    }

    // phase 5: agg = e @ yv (global yv, L2-resident; coalesced 2 rows/iter)
    {
        const int dd = lane & 31, jg = lane >> 5;
        const float* yvg = yv + ((size_t)(b * Ny) << 5);
        float p = 0.f;
        #pragma unroll 8
        for (int j = jg; j < Ny; j += 2)
            p = fmaf(sS[(wv << 7) + j], yvg[(j << 5) + dd], p);
        p += __shfl_xor(p, 32);
        if (jg == 0) sAgg[(wv << 5) + dd] = p;
    }
    __syncthreads();

    // phase 7: node-MLP hidden (T overlays u)
    {
        const float4* w14 = (const float4*)(Wn1 + (tid << 6));
        const float b1 = bn1[tid];
        float acc[TI];
        #pragma unroll
        for (int il = 0; il < TI; ++il) acc[il] = b1;
        #pragma unroll
        for (int k = 0; k < 8; ++k) {
            float4 wa = w14[k];
            #pragma unroll
            for (int il = 0; il < TI; ++il)
                acc[il] += dot4(wa, ((const float4*)(sX + (il << 5)))[k]);
        }
        #pragma unroll
        for (int k = 0; k < 8; ++k) {
            float4 wb = w14[8 + k];
            #pragma unroll
            for (int il = 0; il < TI; ++il)
                acc[il] += dot4(wb, ((const float4*)(sAgg + (il << 5)))[k]);
        }
        __syncthreads();
        #pragma unroll
        for (int il = 0; il < TI; ++il) sUT[(il << 8) + tid] = fmaxf(acc[il], 0.f);
    }
    __syncthreads();

    // phase 8: out = x + T @ Wn2^T + bn2
    {
        const int hg = tid >> 5, dd = tid & 31;
        const float4* w24 = (const float4*)(Wn2 + (dd << 8) + (hg << 5));
        float4 w2r[8];
        #pragma unroll
        for (int k = 0; k < 8; ++k) w2r[k] = w24[k];
        float p[TI] = {0.f, 0.f, 0.f, 0.f};
        #pragma unroll
        for (int k = 0; k < 8; ++k) {
            #pragma unroll
            for (int il = 0; il < TI; ++il)
                p[il] += dot4(w2r[k], ((const float4*)(sUT + (il << 8) + (hg << 5)))[k]);
        }
        #pragma unroll
        for (int il = 0; il < TI; ++il) sPR[(hg << 7) + (il << 5) + dd] = p[il];
    }
    __syncthreads();
    if (tid < 128) {
        int il = tid >> 5, dd = tid & 31;
        float a = bn2[dd] + sX[tid];
        #pragma unroll
        for (int hg = 0; hg < 8; ++hg) a += sPR[(hg << 7) + tid];
        outp[((size_t)(b * Nx + i0 + il)) * 32 + dd] = a;
        if (wPre) sQ[tid] = a;     // keep out rows for tail
    }

    // ---- H-fused pre tail (stage-6 blocks): w/yv for the next stage ----
    if (wPre) {
        __syncthreads();
        if (tid < 128) {           // yv = Wv out + bv
            int il = tid >> 5, dd = tid & 31;
            const float4* wm4 = (const float4*)(Wv + (dd << 5));
            const float4* orow = (const float4*)(sQ + (il << 5));
            float a = bv[dd];
            #pragma unroll
            for (int k = 0; k < 8; ++k) a += dot4(wm4[k], orow[k]);
            yvPre[(((size_t)(b * Nx + i0 + il)) << 5) + dd] = a;
        }
        {                          // w = H out + hb (no yk round-trip)
            const float* hrow = Hm + (tid << 5);
            const float hb0 = hbvec[tid];
            float acc[4];
            #pragma unroll
            for (int il = 0; il < 4; ++il) acc[il] = hb0;
            #pragma unroll
            for (int e = 0; e < 32; ++e) {
                float we = hrow[e];
                #pragma unroll
                for (int il = 0; il < 4; ++il)
                    acc[il] = fmaf(we, sQ[(il << 5) + e], acc[il]);
            }
            float* wbase = wPre + (((size_t)b * 64 + (tid >> 2)) * Nx + i0) * 4 + (tid & 3);
            #pragma unroll
            for (int il = 0; il < 4; ++il)
                wbase[il << 2] = acc[il];
        }
    }
}

// ---------------------------------------------------------------------------
// inter_fused v2: same flag-sync C+D fusion as R8, but __launch_bounds__
// (256,4) — R8's (256,8) forced VGPR=32 and the kernel spilled to scratch
// (WRITE_SIZE inflated 8.1MB, VALUBusy 8%, 271us). VGPR cap 128 removes the
// spills. Progress (no-deadlock) argument no longer needs full residency:
// C-blocks wait on nothing, so any slot cycling through C-blocks drains all
// 1280 producers; the 256 D-blocks can never occupy all >=1024 resident
// slots, so C always has somewhere to run; D-blocks are at the grid tail so
// they are typically scheduled after producers anyway.
// ---------------------------------------------------------------------------
__global__ __launch_bounds__(256, 4) void inter_fused_kernel(
    const float* __restrict__ xA, const float* __restrict__ wA, const float* __restrict__ yvA,
    const float* __restrict__ disA, float* __restrict__ outA,
    const float* __restrict__ xB, const float* __restrict__ wB, const float* __restrict__ yvB,
    const float* __restrict__ disB, float* __restrict__ outB,
    float* __restrict__ w7p, float* __restrict__ yv7p,
    const float* __restrict__ disD, float* __restrict__ outD, float* __restrict__ eD,
    const float* __restrict__ Gm, const float* __restrict__ gvec,
    const float* __restrict__ Hm, const float* __restrict__ hbvec,
    const float* __restrict__ Wv, const float* __restrict__ bv,
    const float* __restrict__ We1, const float* __restrict__ We2,
    const float* __restrict__ Wn1, const float* __restrict__ bn1,
    const float* __restrict__ Wn2, const float* __restrict__ bn2,
    unsigned* __restrict__ flags)
{
    __shared__ __align__(16) float sX[128];
    __shared__ __align__(16) float sQ[128];
    __shared__ __align__(16) float sAgg[128];
    __shared__ __align__(16) float sDis[512];
    __shared__ __align__(16) float sC[256];
    __shared__ __align__(16) float sW2[256];
    __shared__ __align__(16) float sS[512];
    __shared__ __align__(16) float sUT[1024];
    __shared__ __align__(16) float sPR[2048];

    const int blk = (int)blockIdx.x, tid = threadIdx.x;

    if (blk < 1280) {
        // ---- stage C: segment-balanced XCD swizzle over 256 A + 1024 B
        const int xcd = blk & 7, slot = blk >> 3;   // slot 0..159
        int bb;
        if (slot < 32) {
            const int t = (xcd << 5) + slot;        // A task [0,256)
            bb = t >> 3;
            inter_body(xA, NRr, wA, yvA, NHh, disA, outA,
                       nullptr, nullptr, nullptr, t,
                       Gm, gvec, Hm, hbvec, Wv, bv, We1, We2,
                       Wn1, bn1, Wn2, bn2,
                       sX, sQ, sAgg, sDis, sC, sW2, sS, sUT, sPR);
        } else {
            const int t = (xcd << 7) + (slot - 32); // B task [0,1024)
            bb = t >> 5;
            inter_body(xB, NFf, wB, yvB, NFHh, disB, outB,
                       nullptr, w7p, yv7p, t,
                       Gm, gvec, Hm, hbvec, Wv, bv, We1, We2,
                       Wn1, bn1, Wn2, bn2,
                       sX, sQ, sAgg, sDis, sC, sW2, sS, sUT, sPR);
        }
        // release: make this block's writes device-visible, then signal
        __threadfence();
        __syncthreads();
        if (tid == 0) atomicAdd(&flags[bb], 1u);
    } else {
        // ---- stage D: task t, waits for its batch's 40 producers
        const int i = blk - 1280;                   // [0,256)
        const int t = ((i & 7) << 5) + (i >> 3);    // same per-XCD batching
        const int bb = t >> 3;
        if (tid == 0) {
            while (atomicAdd(&flags[bb], 0u) < 40u)
                __builtin_amdgcn_s_sleep(16);
        }
        __syncthreads();
        __threadfence();   // acquire: see producers' plain stores
        inter_body(outA /*robot2*/, NRr, w7p, yv7p, NFf, disD, outD,
                   eD, nullptr, nullptr, t,
                   Gm, gvec, Hm, hbvec, Wv, bv, We1, We2,
                   Wn1, bn1, Wn2, bn2,
                   sX, sQ, sAgg, sDis, sC, sW2, sS, sUT, sPR);
    }
}

// ---------------------------------------------------------------------------
extern "C" void kernel_launch(void* const* d_in, const int* in_sizes, int n_in,
                              void* d_out, int out_size, void* d_ws, size_t ws_size,
                              hipStream_t stream) {
    const float* robot          = (const float*)d_in[0];
    const float* frontier       = (const float*)d_in[1];
    const float* rh             = (const float*)d_in[2];
    const float* fh             = (const float*)d_in[3];
    const float* robot_frontier = (const float*)d_in[4];
    const float* robot_past     = (const float*)d_in[5];
    const float* frontier_past  = (const float*)d_in[6];
    const float* Wq  = (const float*)d_in[7];  const float* bq  = (const float*)d_in[8];
    const float* Wk  = (const float*)d_in[9];  const float* bk  = (const float*)d_in[10];
    const float* Wv  = (const float*)d_in[11]; const float* bv  = (const float*)d_in[12];
    const float* Wn1 = (const float*)d_in[13]; const float* bn1 = (const float*)d_in[14];
    const float* Wn2 = (const float*)d_in[15]; const float* bn2 = (const float*)d_in[16];
    const float* We1 = (const float*)d_in[17]; const float* be1 = (const float*)d_in[18];
    const float* We2 = (const float*)d_in[19];

    float* out = (float*)d_out;
    float* out_robot    = out;            // 32*32*32   = 32768
    float* out_frontier = out + 32768;    // 32*128*32  = 131072
    float* out_rh       = out + 163840;   // 32*64*32   = 65536
    float* out_fh       = out + 229376;   // 32*64*32   = 65536
    float* out_edge     = out + 294912;   // 32*32*128  = 131072

    float* W = (float*)d_ws;
    float* robot1 = W;                 // 32768
    float* robot2 = W + 32768;         // 32768
    float* nf     = W + 65536;         // 131072
    float* w5     = W + 196608;        // 524288 (wT layout)
    float* yv5    = W + 720896;        // 65536
    float* w6     = W + 786432;        // 524288 (wT layout)
    float* yv6    = W + 1310720;       // 65536
    float* w7     = W + 1376256;       // 1048576 (wT layout)
    float* yv7    = W + 2424832;       // 131072 -> 2555904
    float* Gm     = W + 2555904;       // 8192
    float* gvec   = W + 2564096;       // 256
    float* Hm     = W + 2564352;       // 8192
    float* hbvec  = W + 2572544;       // 256 -> ends 2572800
    unsigned* flags = (unsigned*)(W + 2572800);  // 32 uints

    // A: four intra-attentions + merged pre_y tails + G/H blocks (576+32);
    // block 576 also zeroes the flags for launch B.
    intra_kernel<<<608, 256, 0, stream>>>(robot, frontier, rh, fh,
        Wq, bq, Wk, bk, Wv, bv, Wn1, bn1, Wn2, bn2, We1, be1,
        robot1, out_frontier, out_rh, out_fh,
        w5, yv5, w6, yv6, Gm, gvec, Hm, hbvec, flags);

    // B: fused inter (stage C: inter5+inter6 -> flags; stage D: inter7 spins)
    inter_fused_kernel<<<1536, 256, 0, stream>>>(
        robot1, w5, yv5, robot_past, robot2,
        out_frontier, w6, yv6, frontier_past, nf,
        w7, yv7,
        robot_frontier, out_robot, out_edge,
        Gm, gvec, Hm, hbvec, Wv, bv, We1, We2, Wn1, bn1, Wn2, bn2,
        flags);
}